// Round 1
// baseline (517.282 us; speedup 1.0000x reference)
//
#include <hip/hip_runtime.h>
#include <math.h>

// Problem constants (reference: K=256, Q=64, T=500001 -> n = 500000)
#define K_ 256
#define Q_ 64
#define NT 500000

// Workspace layout (in floats):
//  [0]  sum(u2)      (memset 0 before k_u2)
//  [1]  sum(u2^2)    (memset 0 before k_u2)
//  [2]  softplus(raw_beta0)
//  [4 .. 4+Q_+NT)          u2_full  (Q_ init entries + u2)
//  [WS_WT .. +Q_*K_)       wT[j][k] = softplus(raw_w[k][Q_-1-j])  (transposed+reversed)
//  [WS_W0 .. +K_)          softplus(raw_w0)
//  [WS_BETA .. +K_)        softplus(raw_beta)
#define WS_SUMS   0
#define WS_BETA0  2
#define WS_U2FULL 4
#define WS_WT     (WS_U2FULL + Q_ + NT)
#define WS_W0     (WS_WT + Q_*K_)
#define WS_BETA   (WS_W0 + K_)

__device__ __forceinline__ float softplusf(float x) {
    // inputs here are all ~ -4 or -8; guard large x anyway
    return (x > 20.f) ? x : log1pf(__expf(x));
}

// Kernel A: u2[i] = (r[i+1]-a0-a1*r[i])^2; accumulate sum(u2), sum(u2^2)
__global__ void k_u2(const float* __restrict__ r,
                     const float* __restrict__ a0p,
                     const float* __restrict__ a1p,
                     float* __restrict__ ws) {
    int i = blockIdx.x * blockDim.x + threadIdx.x;
    float a0 = a0p[0], a1 = a1p[0];
    float v = 0.f, v2 = 0.f;
    if (i < NT) {
        float u  = r[i + 1] - a0 - a1 * r[i];
        float u2 = u * u;
        ws[WS_U2FULL + Q_ + i] = u2;
        v = u2; v2 = u2 * u2;
    }
    // wave64 reduce
    #pragma unroll
    for (int off = 32; off > 0; off >>= 1) {
        v  += __shfl_down(v,  off, 64);
        v2 += __shfl_down(v2, off, 64);
    }
    if ((threadIdx.x & 63) == 0) {
        atomicAdd(&ws[WS_SUMS],     v);
        atomicAdd(&ws[WS_SUMS + 1], v2);
    }
}

// Kernel B: softplus transforms (w transposed+reversed), var(u2) init fill,
// beta0, and d_out constant term init.
__global__ void k_prep(const float* __restrict__ raw_beta0,
                       const float* __restrict__ raw_beta,
                       const float* __restrict__ raw_w0,
                       const float* __restrict__ raw_w,
                       float* __restrict__ ws,
                       float* __restrict__ out) {
    int idx = blockIdx.x * blockDim.x + threadIdx.x;
    if (idx < Q_ * K_) {
        int k = idx & (K_ - 1);
        int j = idx >> 8;                 // K_ == 256
        ws[WS_WT + idx] = softplusf(raw_w[k * Q_ + (Q_ - 1 - j)]);
    } else if (idx < Q_ * K_ + K_) {
        int k = idx - Q_ * K_;
        ws[WS_W0 + k] = softplusf(raw_w0[k]);
    } else if (idx < Q_ * K_ + 2 * K_) {
        int k = idx - (Q_ * K_ + K_);
        ws[WS_BETA + k] = softplusf(raw_beta[k]);
    } else if (idx < Q_ * K_ + 2 * K_ + Q_) {
        // unbiased var of u2 (ddof=1), redundant per-thread compute is fine
        float s1 = ws[WS_SUMS], s2 = ws[WS_SUMS + 1];
        float n  = (float)NT;
        float var = (s2 - s1 * s1 / n) / (n - 1.f);
        ws[WS_U2FULL + (idx - (Q_ * K_ + 2 * K_))] = var;
        if (idx == Q_ * K_ + 2 * K_) {
            ws[WS_BETA0] = softplusf(raw_beta0[0]);
            // 0.5 * n * log(2*pi)
            out[0] = 0.5f * n * 1.8378770664093453f;
        }
    }
}

// Kernel C: main conv + NLL reduction.
// Lane owns t; 64-float u2 window in VGPRs; wT in LDS read at wave-uniform
// addresses (broadcast ds_read_b128, 4 FMAs per read, 4 indep chains).
__launch_bounds__(512, 4)
__global__ void k_main(const float* __restrict__ ws, float* __restrict__ out) {
    __shared__ float wT[Q_ * K_];   // exactly 64 KiB
    {
        const float* gwT = ws + WS_WT;
        for (int i = threadIdx.x; i < Q_ * K_; i += 512)
            wT[i] = gwT[i];
    }
    __syncthreads();

    const float* u2f = ws + WS_U2FULL;
    int t = blockIdx.x * 512 + threadIdx.x;
    bool active = (t < NT);
    int tc = active ? t : (NT - 1);

    float win[Q_];
    #pragma unroll
    for (int j = 0; j < Q_; ++j) win[j] = u2f[tc + j];
    float u2t = u2f[Q_ + tc];

    const float* w0  = ws + WS_W0;
    const float* bet = ws + WS_BETA;

    float sig = 0.f;
    #pragma unroll 1
    for (int kg = 0; kg < K_ / 4; ++kg) {
        float4 acc = *(const float4*)(w0 + 4 * kg);      // wave-uniform
        #pragma unroll
        for (int j = 0; j < Q_; ++j) {
            float4 wv = *(const float4*)(&wT[j * K_ + 4 * kg]);  // broadcast
            acc.x = fmaf(wv.x, win[j], acc.x);
            acc.y = fmaf(wv.y, win[j], acc.y);
            acc.z = fmaf(wv.z, win[j], acc.z);
            acc.w = fmaf(wv.w, win[j], acc.w);
        }
        float4 b = *(const float4*)(bet + 4 * kg);       // wave-uniform
        sig += b.x * fmaxf(acc.x, 0.f) + b.y * fmaxf(acc.y, 0.f)
             + b.z * fmaxf(acc.z, 0.f) + b.w * fmaxf(acc.w, 0.f);
    }

    float sig2 = ws[WS_BETA0] + sig + 1e-8f;
    float val  = active ? (__logf(sig2) + u2t / sig2) : 0.f;

    #pragma unroll
    for (int off = 32; off > 0; off >>= 1)
        val += __shfl_down(val, off, 64);
    if ((threadIdx.x & 63) == 0)
        atomicAdd(out, 0.5f * val);
}

extern "C" void kernel_launch(void* const* d_in, const int* in_sizes, int n_in,
                              void* d_out, int out_size, void* d_ws, size_t ws_size,
                              hipStream_t stream) {
    const float* r        = (const float*)d_in[0];
    const float* a0       = (const float*)d_in[1];
    const float* a1       = (const float*)d_in[2];
    const float* raw_b0   = (const float*)d_in[3];
    const float* raw_beta = (const float*)d_in[4];
    const float* raw_w0   = (const float*)d_in[5];
    const float* raw_w    = (const float*)d_in[6];
    float* out = (float*)d_out;
    float* ws  = (float*)d_ws;

    // zero the two reduction scalars (ws is poisoned 0xAA before each launch)
    hipMemsetAsync(ws, 0, 2 * sizeof(float), stream);

    k_u2<<<(NT + 255) / 256, 256, 0, stream>>>(r, a0, a1, ws);

    int prep_threads = Q_ * K_ + 2 * K_ + Q_;   // 16960
    k_prep<<<(prep_threads + 255) / 256, 256, 0, stream>>>(
        raw_b0, raw_beta, raw_w0, raw_w, ws, out);

    k_main<<<(NT + 511) / 512, 512, 0, stream>>>(ws, out);
}

// Round 2
// 458.026 us; speedup vs baseline: 1.1294x; 1.1294x over previous
//
#include <hip/hip_runtime.h>
#include <math.h>

// Problem constants (reference: K=256, Q=64, T=500001 -> n = 500000)
#define K_ 256
#define Q_ 64
#define NT 500000

// Workspace layout (in floats):
//  [0]  sum(u2)      (memset 0 before k_u2)
//  [1]  sum(u2^2)    (memset 0 before k_u2)
//  [2]  softplus(raw_beta0)
//  [4 .. 4+Q_+NT)          u2_full  (Q_ init entries + u2)
//  [WS_WT .. +Q_*K_)       wT[j][k] = softplus(raw_w[k][Q_-1-j])  (transposed+reversed)
//  [WS_W0 .. +K_)          softplus(raw_w0)
//  [WS_BETA .. +K_)        softplus(raw_beta)
#define WS_SUMS   0
#define WS_BETA0  2
#define WS_U2FULL 4
#define WS_WT     (WS_U2FULL + Q_ + NT)
#define WS_W0     (WS_WT + Q_*K_)
#define WS_BETA   (WS_W0 + K_)

__device__ __forceinline__ float softplusf(float x) {
    return (x > 20.f) ? x : log1pf(__expf(x));
}

// Kernel A: u2[i] = (r[i+1]-a0-a1*r[i])^2; accumulate sum(u2), sum(u2^2)
__global__ void k_u2(const float* __restrict__ r,
                     const float* __restrict__ a0p,
                     const float* __restrict__ a1p,
                     float* __restrict__ ws) {
    int i = blockIdx.x * blockDim.x + threadIdx.x;
    float a0 = a0p[0], a1 = a1p[0];
    float v = 0.f, v2 = 0.f;
    if (i < NT) {
        float u  = r[i + 1] - a0 - a1 * r[i];
        float u2 = u * u;
        ws[WS_U2FULL + Q_ + i] = u2;
        v = u2; v2 = u2 * u2;
    }
    #pragma unroll
    for (int off = 32; off > 0; off >>= 1) {
        v  += __shfl_down(v,  off, 64);
        v2 += __shfl_down(v2, off, 64);
    }
    if ((threadIdx.x & 63) == 0) {
        atomicAdd(&ws[WS_SUMS],     v);
        atomicAdd(&ws[WS_SUMS + 1], v2);
    }
}

// Kernel B: softplus transforms (w transposed+reversed), var(u2) init fill,
// beta0, and d_out constant term init.
__global__ void k_prep(const float* __restrict__ raw_beta0,
                       const float* __restrict__ raw_beta,
                       const float* __restrict__ raw_w0,
                       const float* __restrict__ raw_w,
                       float* __restrict__ ws,
                       float* __restrict__ out) {
    int idx = blockIdx.x * blockDim.x + threadIdx.x;
    if (idx < Q_ * K_) {
        int k = idx & (K_ - 1);
        int j = idx >> 8;                 // K_ == 256
        ws[WS_WT + idx] = softplusf(raw_w[k * Q_ + (Q_ - 1 - j)]);
    } else if (idx < Q_ * K_ + K_) {
        int k = idx - Q_ * K_;
        ws[WS_W0 + k] = softplusf(raw_w0[k]);
    } else if (idx < Q_ * K_ + 2 * K_) {
        int k = idx - (Q_ * K_ + K_);
        ws[WS_BETA + k] = softplusf(raw_beta[k]);
    } else if (idx < Q_ * K_ + 2 * K_ + Q_) {
        float s1 = ws[WS_SUMS], s2 = ws[WS_SUMS + 1];
        float n  = (float)NT;
        float var = (s2 - s1 * s1 / n) / (n - 1.f);
        ws[WS_U2FULL + (idx - (Q_ * K_ + 2 * K_))] = var;
        if (idx == Q_ * K_ + 2 * K_) {
            ws[WS_BETA0] = softplusf(raw_beta0[0]);
            out[0] = 0.5f * n * 1.8378770664093453f;   // 0.5*n*log(2*pi)
        }
    }
}

// Kernel C: main conv + NLL reduction.
// Lane owns 2 consecutive t's (rolling 1-reg window, 1 global L1-hit load
// per j). Weights read at wave-uniform addresses from global -> compiler
// scalarizes to s_load (scalar pipe), v_fma takes SGPR weight operand.
// K chunked by 16 -> acc = 2x4 float4 = 32 VGPRs, 32 indep FMA chains.
__launch_bounds__(256, 4)
__global__ void k_main(const float* __restrict__ ws, float* __restrict__ out) {
    const float* __restrict__ u2f = ws + WS_U2FULL;
    const float* __restrict__ wT  = ws + WS_WT;
    const float* __restrict__ w0  = ws + WS_W0;
    const float* __restrict__ bet = ws + WS_BETA;

    int t0 = blockIdx.x * 512 + threadIdx.x * 2;   // NT even, t0 even -> t0,t1 both valid or both not
    bool active = (t0 < NT);
    int tc = active ? t0 : 0;

    float sig0 = 0.f, sig1 = 0.f;

    #pragma unroll 1
    for (int kc = 0; kc < K_; kc += 16) {
        float4 acc0[4], acc1[4];
        #pragma unroll
        for (int c = 0; c < 4; ++c) {
            float4 w0v = *(const float4*)(w0 + kc + 4 * c);   // uniform -> s_load
            acc0[c] = w0v;
            acc1[c] = w0v;
        }
        float a = u2f[tc];                 // t0 window val at j=0
        const float* wrow = wT + kc;
        #pragma unroll 4
        for (int j = 0; j < Q_; ++j) {
            float b = u2f[tc + j + 1];     // t1's j-val == t0's (j+1)-val
            const float4* wr = (const float4*)(wrow + j * K_); // uniform -> s_load
            #pragma unroll
            for (int c = 0; c < 4; ++c) {
                float4 wv = wr[c];
                acc0[c].x = fmaf(wv.x, a, acc0[c].x);
                acc0[c].y = fmaf(wv.y, a, acc0[c].y);
                acc0[c].z = fmaf(wv.z, a, acc0[c].z);
                acc0[c].w = fmaf(wv.w, a, acc0[c].w);
                acc1[c].x = fmaf(wv.x, b, acc1[c].x);
                acc1[c].y = fmaf(wv.y, b, acc1[c].y);
                acc1[c].z = fmaf(wv.z, b, acc1[c].z);
                acc1[c].w = fmaf(wv.w, b, acc1[c].w);
            }
            a = b;
        }
        #pragma unroll
        for (int c = 0; c < 4; ++c) {
            float4 bv = *(const float4*)(bet + kc + 4 * c);   // uniform -> s_load
            sig0 += bv.x * fmaxf(acc0[c].x, 0.f) + bv.y * fmaxf(acc0[c].y, 0.f)
                  + bv.z * fmaxf(acc0[c].z, 0.f) + bv.w * fmaxf(acc0[c].w, 0.f);
            sig1 += bv.x * fmaxf(acc1[c].x, 0.f) + bv.y * fmaxf(acc1[c].y, 0.f)
                  + bv.z * fmaxf(acc1[c].z, 0.f) + bv.w * fmaxf(acc1[c].w, 0.f);
        }
    }

    float b0 = ws[WS_BETA0];
    float s0 = b0 + sig0 + 1e-8f;
    float s1 = b0 + sig1 + 1e-8f;
    float u20 = u2f[Q_ + tc];
    float u21 = u2f[Q_ + tc + 1];
    float val = active ? (__logf(s0) + u20 / s0 + __logf(s1) + u21 / s1) : 0.f;

    #pragma unroll
    for (int off = 32; off > 0; off >>= 1)
        val += __shfl_down(val, off, 64);
    if ((threadIdx.x & 63) == 0)
        atomicAdd(out, 0.5f * val);
}

extern "C" void kernel_launch(void* const* d_in, const int* in_sizes, int n_in,
                              void* d_out, int out_size, void* d_ws, size_t ws_size,
                              hipStream_t stream) {
    const float* r        = (const float*)d_in[0];
    const float* a0       = (const float*)d_in[1];
    const float* a1       = (const float*)d_in[2];
    const float* raw_b0   = (const float*)d_in[3];
    const float* raw_beta = (const float*)d_in[4];
    const float* raw_w0   = (const float*)d_in[5];
    const float* raw_w    = (const float*)d_in[6];
    float* out = (float*)d_out;
    float* ws  = (float*)d_ws;

    hipMemsetAsync(ws, 0, 2 * sizeof(float), stream);

    k_u2<<<(NT + 255) / 256, 256, 0, stream>>>(r, a0, a1, ws);

    int prep_threads = Q_ * K_ + 2 * K_ + Q_;   // 16960
    k_prep<<<(prep_threads + 255) / 256, 256, 0, stream>>>(
        raw_b0, raw_beta, raw_w0, raw_w, ws, out);

    // 2 t's per thread -> 512 t's per 256-thread block
    k_main<<<(NT + 511) / 512, 256, 0, stream>>>(ws, out);
}

// Round 3
// 315.233 us; speedup vs baseline: 1.6410x; 1.4530x over previous
//
#include <hip/hip_runtime.h>
#include <math.h>

// Problem constants (reference: K=256, Q=64, T=500001 -> n = 500000)
#define K_ 256
#define Q_ 64
#define NT 500000
#define NTILES (NT / 16)      // 31250 t-tiles of 16
#define TT_ 16                // t-tiles per block

// Workspace layout (float offsets):
//  [0]  sum(u2)   [1] sum(u2^2)   (memset 0 before k_u2)
//  [2]  softplus(raw_beta0)
//  [WS_U2   .. +Q_+NT)   u2_full fp32
//  [WS_U2B0 .. )         bf16 u2_full            (ushort, len Q_+NT)
//  [WS_U2B1 .. )         bf16 u2_full shifted+1  (ushort, len Q_+NT; [e]=u2f[e+1])
//  [WS_BPACK .. )        B in MFMA fragment order (ushort, 16*2*64*8 = 16384)
//  [WS_W0 .. +K_)        softplus(raw_w0) fp32
//  [WS_BETA .. +K_)      softplus(raw_beta) fp32
#define WS_SUMS   0
#define WS_BETA0  2
#define WS_U2     4
#define WS_U2B0   (WS_U2 + Q_ + NT)                 // 500068
#define WS_U2B1   (WS_U2B0 + (Q_ + NT + 1) / 2)     // 750100
#define WS_BPACK  (WS_U2B1 + (Q_ + NT + 1) / 2)     // 1000132
#define WS_W0     (WS_BPACK + 8192)                 // 1008324
#define WS_BETA   (WS_W0 + K_)

typedef __attribute__((ext_vector_type(8))) __bf16 bf16x8;
typedef __attribute__((ext_vector_type(4))) float  f32x4;

__device__ __forceinline__ float softplusf(float x) {
    return (x > 20.f) ? x : log1pf(__expf(x));
}

__device__ __forceinline__ unsigned short f2bf(float f) {
    unsigned int u = __float_as_uint(f);
    u = u + 0x7FFFu + ((u >> 16) & 1u);   // RNE (positive normals here)
    return (unsigned short)(u >> 16);
}

// Kernel A: u2[i] = (r[i+1]-a0-a1*r[i])^2; fp32 + two bf16 copies; sum, sumsq
__global__ void k_u2(const float* __restrict__ r,
                     const float* __restrict__ a0p,
                     const float* __restrict__ a1p,
                     float* __restrict__ ws) {
    int i = blockIdx.x * blockDim.x + threadIdx.x;
    float a0 = a0p[0], a1 = a1p[0];
    float v = 0.f, v2 = 0.f;
    if (i < NT) {
        float u  = r[i + 1] - a0 - a1 * r[i];
        float u2 = u * u;
        ws[WS_U2 + Q_ + i] = u2;
        unsigned short b = f2bf(u2);
        ((unsigned short*)(ws + WS_U2B0))[Q_ + i]     = b;
        ((unsigned short*)(ws + WS_U2B1))[Q_ + i - 1] = b;   // [e] = u2f[e+1]
        v = u2; v2 = u2 * u2;
    }
    #pragma unroll
    for (int off = 32; off > 0; off >>= 1) {
        v  += __shfl_down(v,  off, 64);
        v2 += __shfl_down(v2, off, 64);
    }
    if ((threadIdx.x & 63) == 0) {
        atomicAdd(&ws[WS_SUMS],     v);
        atomicAdd(&ws[WS_SUMS + 1], v2);
    }
}

// Kernel B: pack B fragments (bf16), softplus w0/beta, var-init entries, beta0.
// Bpack layout: frag (kc,s): 64 lanes x 8 bf16, entry
//   Bpack[((kc*2+s)*64 + l)*8 + jj] = W'[32s + 8*(l>>4) + jj][kc*16 + (l&15)]
// where W'[j][kout] = softplus(raw_w[kout][63-j]).
__global__ void k_prep(const float* __restrict__ raw_beta0,
                       const float* __restrict__ raw_beta,
                       const float* __restrict__ raw_w0,
                       const float* __restrict__ raw_w,
                       float* __restrict__ ws,
                       float* __restrict__ out) {
    int idx = blockIdx.x * blockDim.x + threadIdx.x;
    if (idx < 16384) {
        int jj = idx & 7, l = (idx >> 3) & 63, s = (idx >> 9) & 1, kc = idx >> 10;
        int j    = 32 * s + 8 * (l >> 4) + jj;
        int kout = kc * 16 + (l & 15);
        ((unsigned short*)(ws + WS_BPACK))[idx] =
            f2bf(softplusf(raw_w[kout * Q_ + (Q_ - 1 - j)]));
    } else if (idx < 16384 + K_) {
        int k = idx - 16384;
        ws[WS_W0 + k] = softplusf(raw_w0[k]);
    } else if (idx < 16384 + 2 * K_) {
        int k = idx - (16384 + K_);
        ws[WS_BETA + k] = softplusf(raw_beta[k]);
    } else if (idx < 16384 + 2 * K_ + Q_) {
        int j = idx - (16384 + 2 * K_);
        float s1 = ws[WS_SUMS], s2 = ws[WS_SUMS + 1];
        float n  = (float)NT;
        float var = (s2 - s1 * s1 / n) / (n - 1.f);
        unsigned short b = f2bf(var);
        ((unsigned short*)(ws + WS_U2B0))[j] = b;
        if (j < Q_ - 1) ((unsigned short*)(ws + WS_U2B1))[j] = b;
        if (j == 0) {
            ws[WS_BETA0] = softplusf(raw_beta0[0]);
            out[0] = 0.5f * n * 1.8378770664093453f;   // 0.5*n*log(2*pi)
        }
    }
}

// Kernel C: bf16 MFMA sliding-window GEMM + fused NLL epilogue.
// Block = 4 waves; wave w owns kout tiles kc = 4w..4w+3 (B frags in VGPRs).
// Per t-tile (16 t's): 2 A frags (16B loads, parity-split arrays for 4B
// alignment), 8 MFMA 16x16x32_bf16, relu*beta epilogue, quad butterfly,
// LDS combine across waves, log+ratio by threads 0..15.
__launch_bounds__(256, 4)
__global__ void k_main(const float* __restrict__ ws, float* __restrict__ out) {
    __shared__ __align__(16) float sigbuf[2][4][16];

    int tid = threadIdx.x;
    int l = tid & 63, w = tid >> 6;
    int m = l & 15, q = l >> 4;

    const unsigned short* __restrict__ bp = (const unsigned short*)(ws + WS_BPACK);
    const float* __restrict__ w0  = ws + WS_W0;
    const float* __restrict__ bet = ws + WS_BETA;
    const float* __restrict__ u2f = ws + WS_U2;
    float beta0v = ws[WS_BETA0];

    // Preload B fragments (4 tiles x 2 k-slices) and per-lane beta/w0.
    bf16x8 Bf[4][2];
    float betv[4], w0v[4];
    #pragma unroll
    for (int i = 0; i < 4; ++i) {
        int kc = w * 4 + i;
        #pragma unroll
        for (int s = 0; s < 2; ++s)
            __builtin_memcpy(&Bf[i][s], bp + ((kc * 2 + s) * 64 + l) * 8, 16);
        betv[i] = bet[kc * 16 + m];
        w0v[i]  = w0[kc * 16 + m];
    }

    // A-fragment addressing: lane needs u2full[s0 .. s0+7], s0 = t0+m+8q (+32).
    // parity(s0) = m&1 (t0 multiple of 16): even -> u2b0[s0], odd -> u2b1[s0-1].
    int par = m & 1;
    const char* abase = (const char*)(ws + (par ? WS_U2B1 : WS_U2B0));
    int tile0 = blockIdx.x * TT_;
    int aoff = (tile0 * 16 + m + 8 * q - par) * 2;   // bytes

    float accloc = 0.f;

    for (int it = 0; it < TT_; ++it) {
        bool valid = (tile0 + it) < NTILES;          // block-uniform
        if (valid) {
            bf16x8 A0, A1;
            __builtin_memcpy(&A0, abase + aoff, 16);
            __builtin_memcpy(&A1, abase + aoff + 64, 16);   // +32 elements

            float p[4] = {0.f, 0.f, 0.f, 0.f};
            #pragma unroll
            for (int i = 0; i < 4; ++i) {
                f32x4 acc = {w0v[i], w0v[i], w0v[i], w0v[i]};
                acc = __builtin_amdgcn_mfma_f32_16x16x32_bf16(A0, Bf[i][0], acc, 0, 0, 0);
                acc = __builtin_amdgcn_mfma_f32_16x16x32_bf16(A1, Bf[i][1], acc, 0, 0, 0);
                #pragma unroll
                for (int rr = 0; rr < 4; ++rr)
                    p[rr] = fmaf(betv[i], fmaxf(acc[rr], 0.f), p[rr]);
            }
            // reduce across the 16 cols (lanes within quad)
            #pragma unroll
            for (int mask = 1; mask < 16; mask <<= 1) {
                #pragma unroll
                for (int rr = 0; rr < 4; ++rr)
                    p[rr] += __shfl_xor(p[rr], mask, 64);
            }
            if (m == 0) {
                float4 v4 = make_float4(p[0], p[1], p[2], p[3]);
                *(float4*)&sigbuf[it & 1][w][q * 4] = v4;   // rows q*4..q*4+3
            }
        }
        aoff += 32;
        __syncthreads();
        if (valid && tid < 16) {
            float s = sigbuf[it & 1][0][tid] + sigbuf[it & 1][1][tid]
                    + sigbuf[it & 1][2][tid] + sigbuf[it & 1][3][tid];
            float sg = beta0v + s + 1e-8f;
            int t = (tile0 + it) * 16 + tid;
            accloc += __logf(sg) + u2f[Q_ + t] / sg;
        }
    }

    #pragma unroll
    for (int mask = 1; mask < 16; mask <<= 1)
        accloc += __shfl_xor(accloc, mask, 64);
    if (tid == 0) atomicAdd(out, 0.5f * accloc);
}

extern "C" void kernel_launch(void* const* d_in, const int* in_sizes, int n_in,
                              void* d_out, int out_size, void* d_ws, size_t ws_size,
                              hipStream_t stream) {
    const float* r        = (const float*)d_in[0];
    const float* a0       = (const float*)d_in[1];
    const float* a1       = (const float*)d_in[2];
    const float* raw_b0   = (const float*)d_in[3];
    const float* raw_beta = (const float*)d_in[4];
    const float* raw_w0   = (const float*)d_in[5];
    const float* raw_w    = (const float*)d_in[6];
    float* out = (float*)d_out;
    float* ws  = (float*)d_ws;

    hipMemsetAsync(ws, 0, 2 * sizeof(float), stream);

    k_u2<<<(NT + 255) / 256, 256, 0, stream>>>(r, a0, a1, ws);

    int prep_threads = 16384 + 2 * K_ + Q_;   // 16960
    k_prep<<<(prep_threads + 255) / 256, 256, 0, stream>>>(
        raw_b0, raw_beta, raw_w0, raw_w, ws, out);

    int grid = (NTILES + TT_ - 1) / TT_;      // 1954
    k_main<<<grid, 256, 0, stream>>>(ws, out);
}

// Round 4
// 124.797 us; speedup vs baseline: 4.1450x; 2.5260x over previous
//
#include <hip/hip_runtime.h>
#include <math.h>

// Problem constants (reference: K=256, Q=64, T=500001 -> n = 500000)
#define K_ 256
#define Q_ 64
#define NT 500000
#define NTILES (NT / 16)      // 31250 t-tiles of 16
#define TT_ 16                // t-tiles per block
#define NBLK ((NT + 255) / 256)   // 1954 k_u2 blocks

// Workspace layout (float offsets):
//  [2]  softplus(raw_beta0)
//  [WS_U2   .. +Q_+NT)   u2_full fp32
//  [WS_U2B0 .. )         bf16 u2_full            (ushort, len Q_+NT)
//  [WS_U2B1 .. )         bf16 u2_full shifted+1  (ushort, len Q_+NT; [e]=u2f[e+1])
//  [WS_BPACK .. )        B in MFMA fragment order (ushort, 16*2*64*8 = 16384)
//  [WS_W0 .. +K_)        softplus(raw_w0) fp32
//  [WS_BETA .. +K_)      softplus(raw_beta) fp32
//  [WS_PART .. +2048)    per-block sum(u2) partials
//  [WS_PART2 .. +2048)   per-block sum(u2^2) partials
#define WS_BETA0  2
#define WS_U2     4
#define WS_U2B0   (WS_U2 + Q_ + NT)                 // 500068
#define WS_U2B1   (WS_U2B0 + (Q_ + NT + 1) / 2)     // 750100
#define WS_BPACK  (WS_U2B1 + (Q_ + NT + 1) / 2)     // 1000132
#define WS_W0     (WS_BPACK + 8192)                 // 1008324
#define WS_BETA   (WS_W0 + K_)
#define WS_PART   (WS_BETA + K_)
#define WS_PART2  (WS_PART + 2048)

typedef __attribute__((ext_vector_type(8))) __bf16 bf16x8;
typedef __attribute__((ext_vector_type(4))) float  f32x4;

__device__ __forceinline__ float softplusf(float x) {
    return (x > 20.f) ? x : log1pf(__expf(x));
}

__device__ __forceinline__ unsigned short f2bf(float f) {
    unsigned int u = __float_as_uint(f);
    u = u + 0x7FFFu + ((u >> 16) & 1u);   // RNE (positive normals here)
    return (unsigned short)(u >> 16);
}

// Kernel A: u2[i] = (r[i+1]-a0-a1*r[i])^2; fp32 + two bf16 copies.
// Per-block reduction -> plain partial stores (NO atomics — R3 showed the
// per-wave same-cacheline atomics serialized at ~31 cyc each = 201 us).
__global__ void k_u2(const float* __restrict__ r,
                     const float* __restrict__ a0p,
                     const float* __restrict__ a1p,
                     float* __restrict__ ws) {
    __shared__ float red[8];
    int i = blockIdx.x * blockDim.x + threadIdx.x;
    float a0 = a0p[0], a1 = a1p[0];
    float v = 0.f, v2 = 0.f;
    if (i < NT) {
        float u  = r[i + 1] - a0 - a1 * r[i];
        float u2 = u * u;
        ws[WS_U2 + Q_ + i] = u2;
        unsigned short b = f2bf(u2);
        ((unsigned short*)(ws + WS_U2B0))[Q_ + i]     = b;
        ((unsigned short*)(ws + WS_U2B1))[Q_ + i - 1] = b;   // [e] = u2f[e+1]
        v = u2; v2 = u2 * u2;
    }
    #pragma unroll
    for (int off = 32; off > 0; off >>= 1) {
        v  += __shfl_down(v,  off, 64);
        v2 += __shfl_down(v2, off, 64);
    }
    int wv = threadIdx.x >> 6;
    if ((threadIdx.x & 63) == 0) { red[wv * 2] = v; red[wv * 2 + 1] = v2; }
    __syncthreads();
    if (threadIdx.x == 0) {
        ws[WS_PART  + blockIdx.x] = red[0] + red[2] + red[4] + red[6];
        ws[WS_PART2 + blockIdx.x] = red[1] + red[3] + red[5] + red[7];
    }
}

// Kernel B: pack B fragments (bf16), softplus w0/beta, var-init entries, beta0.
// Bpack layout: frag (kc,s): 64 lanes x 8 bf16, entry
//   Bpack[((kc*2+s)*64 + l)*8 + jj] = W'[32s + 8*(l>>4) + jj][kc*16 + (l&15)]
// where W'[j][kout] = softplus(raw_w[kout][63-j]).
// The var branch is one aligned full wave (threads 16896..16959): it reduces
// the NBLK partials itself (strided loads + butterfly) — no atomics.
__global__ void k_prep(const float* __restrict__ raw_beta0,
                       const float* __restrict__ raw_beta,
                       const float* __restrict__ raw_w0,
                       const float* __restrict__ raw_w,
                       float* __restrict__ ws,
                       float* __restrict__ out) {
    int idx = blockIdx.x * blockDim.x + threadIdx.x;
    if (idx < 16384) {
        int jj = idx & 7, l = (idx >> 3) & 63, s = (idx >> 9) & 1, kc = idx >> 10;
        int j    = 32 * s + 8 * (l >> 4) + jj;
        int kout = kc * 16 + (l & 15);
        ((unsigned short*)(ws + WS_BPACK))[idx] =
            f2bf(softplusf(raw_w[kout * Q_ + (Q_ - 1 - j)]));
    } else if (idx < 16384 + K_) {
        int k = idx - 16384;
        ws[WS_W0 + k] = softplusf(raw_w0[k]);
    } else if (idx < 16384 + 2 * K_) {
        int k = idx - (16384 + K_);
        ws[WS_BETA + k] = softplusf(raw_beta[k]);
    } else if (idx < 16384 + 2 * K_ + Q_) {
        int j = idx - (16384 + 2 * K_);   // 0..63 == lane id (aligned wave)
        float s1 = 0.f, s2 = 0.f;
        for (int p = j; p < NBLK; p += 64) {
            s1 += ws[WS_PART  + p];
            s2 += ws[WS_PART2 + p];
        }
        #pragma unroll
        for (int mask = 1; mask < 64; mask <<= 1) {
            s1 += __shfl_xor(s1, mask, 64);
            s2 += __shfl_xor(s2, mask, 64);
        }
        float n  = (float)NT;
        float var = (s2 - s1 * s1 / n) / (n - 1.f);
        unsigned short b = f2bf(var);
        ((unsigned short*)(ws + WS_U2B0))[j] = b;
        if (j < Q_ - 1) ((unsigned short*)(ws + WS_U2B1))[j] = b;
        if (j == 0) {
            ws[WS_BETA0] = softplusf(raw_beta0[0]);
            out[0] = 0.5f * n * 1.8378770664093453f;   // 0.5*n*log(2*pi)
        }
    }
}

// Kernel C: bf16 MFMA sliding-window GEMM + fused NLL epilogue.
// Block = 4 waves; wave w owns kout tiles kc = 4w..4w+3 (B frags in VGPRs).
// Per t-tile (16 t's): 2 A frags (16B loads, parity-split arrays for 4B
// alignment), 8 MFMA 16x16x32_bf16, relu*beta epilogue, quad butterfly,
// LDS combine across waves, log+ratio by threads 0..15.
__launch_bounds__(256, 4)
__global__ void k_main(const float* __restrict__ ws, float* __restrict__ out) {
    __shared__ __align__(16) float sigbuf[2][4][16];

    int tid = threadIdx.x;
    int l = tid & 63, w = tid >> 6;
    int m = l & 15, q = l >> 4;

    const unsigned short* __restrict__ bp = (const unsigned short*)(ws + WS_BPACK);
    const float* __restrict__ w0  = ws + WS_W0;
    const float* __restrict__ bet = ws + WS_BETA;
    const float* __restrict__ u2f = ws + WS_U2;
    float beta0v = ws[WS_BETA0];

    // Preload B fragments (4 tiles x 2 k-slices) and per-lane beta/w0.
    bf16x8 Bf[4][2];
    float betv[4], w0v[4];
    #pragma unroll
    for (int i = 0; i < 4; ++i) {
        int kc = w * 4 + i;
        #pragma unroll
        for (int s = 0; s < 2; ++s)
            __builtin_memcpy(&Bf[i][s], bp + ((kc * 2 + s) * 64 + l) * 8, 16);
        betv[i] = bet[kc * 16 + m];
        w0v[i]  = w0[kc * 16 + m];
    }

    // A-fragment addressing: lane needs u2full[s0 .. s0+7], s0 = t0+m+8q (+32).
    // parity(s0) = m&1 (t0 multiple of 16): even -> u2b0[s0], odd -> u2b1[s0-1].
    int par = m & 1;
    const char* abase = (const char*)(ws + (par ? WS_U2B1 : WS_U2B0));
    int tile0 = blockIdx.x * TT_;
    int aoff = (tile0 * 16 + m + 8 * q - par) * 2;   // bytes

    float accloc = 0.f;

    for (int it = 0; it < TT_; ++it) {
        bool valid = (tile0 + it) < NTILES;          // block-uniform
        if (valid) {
            bf16x8 A0, A1;
            __builtin_memcpy(&A0, abase + aoff, 16);
            __builtin_memcpy(&A1, abase + aoff + 64, 16);   // +32 elements

            float p[4] = {0.f, 0.f, 0.f, 0.f};
            #pragma unroll
            for (int i = 0; i < 4; ++i) {
                f32x4 acc = {w0v[i], w0v[i], w0v[i], w0v[i]};
                acc = __builtin_amdgcn_mfma_f32_16x16x32_bf16(A0, Bf[i][0], acc, 0, 0, 0);
                acc = __builtin_amdgcn_mfma_f32_16x16x32_bf16(A1, Bf[i][1], acc, 0, 0, 0);
                #pragma unroll
                for (int rr = 0; rr < 4; ++rr)
                    p[rr] = fmaf(betv[i], fmaxf(acc[rr], 0.f), p[rr]);
            }
            // reduce across the 16 cols (lanes within quad)
            #pragma unroll
            for (int mask = 1; mask < 16; mask <<= 1) {
                #pragma unroll
                for (int rr = 0; rr < 4; ++rr)
                    p[rr] += __shfl_xor(p[rr], mask, 64);
            }
            if (m == 0) {
                float4 v4 = make_float4(p[0], p[1], p[2], p[3]);
                *(float4*)&sigbuf[it & 1][w][q * 4] = v4;   // rows q*4..q*4+3
            }
        }
        aoff += 32;
        __syncthreads();
        if (valid && tid < 16) {
            float s = sigbuf[it & 1][0][tid] + sigbuf[it & 1][1][tid]
                    + sigbuf[it & 1][2][tid] + sigbuf[it & 1][3][tid];
            float sg = beta0v + s + 1e-8f;
            int t = (tile0 + it) * 16 + tid;
            accloc += __logf(sg) + u2f[Q_ + t] / sg;
        }
    }

    #pragma unroll
    for (int mask = 1; mask < 16; mask <<= 1)
        accloc += __shfl_xor(accloc, mask, 64);
    if (tid == 0) atomicAdd(out, 0.5f * accloc);
}

extern "C" void kernel_launch(void* const* d_in, const int* in_sizes, int n_in,
                              void* d_out, int out_size, void* d_ws, size_t ws_size,
                              hipStream_t stream) {
    const float* r        = (const float*)d_in[0];
    const float* a0       = (const float*)d_in[1];
    const float* a1       = (const float*)d_in[2];
    const float* raw_b0   = (const float*)d_in[3];
    const float* raw_beta = (const float*)d_in[4];
    const float* raw_w0   = (const float*)d_in[5];
    const float* raw_w    = (const float*)d_in[6];
    float* out = (float*)d_out;
    float* ws  = (float*)d_ws;

    k_u2<<<NBLK, 256, 0, stream>>>(r, a0, a1, ws);

    int prep_threads = 16384 + 2 * K_ + Q_;   // 16960
    k_prep<<<(prep_threads + 255) / 256, 256, 0, stream>>>(
        raw_b0, raw_beta, raw_w0, raw_w, ws, out);

    int grid = (NTILES + TT_ - 1) / TT_;      // 1954
    k_main<<<grid, 256, 0, stream>>>(ws, out);
}

// Round 5
// 118.426 us; speedup vs baseline: 4.3680x; 1.0538x over previous
//
#include <hip/hip_runtime.h>
#include <math.h>

// Problem constants (reference: K=256, Q=64, T=500001 -> n = 500000)
#define K_ 256
#define Q_ 64
#define NT 500000
#define NTILES (NT / 16)      // 31250 t-tiles of 16
#define TT_ 16                // t-tiles per block
#define NBLK ((NT + 255) / 256)   // 1954 k_u2 blocks

// Workspace layout (float offsets):
//  [2]  softplus(raw_beta0)
//  [WS_U2   .. +Q_+NT)   u2_full fp32
//  [WS_U2B0 .. )         bf16 u2_full            (ushort, len Q_+NT)
//  [WS_U2B1 .. )         bf16 u2_full shifted+1  (ushort, len Q_+NT; [e]=u2f[e+1])
//  [WS_BPACK .. )        B in MFMA fragment order (ushort, 16*2*64*8 = 16384)
//  [WS_W0 .. +K_)        softplus(raw_w0) fp32
//  [WS_BETA .. +K_)      softplus(raw_beta) fp32
//  [WS_PART .. +2048)    per-block sum(u2) partials
//  [WS_PART2 .. +2048)   per-block sum(u2^2) partials
#define WS_BETA0  2
#define WS_U2     4
#define WS_U2B0   (WS_U2 + Q_ + NT)                 // 500068
#define WS_U2B1   (WS_U2B0 + (Q_ + NT + 1) / 2)     // 750100
#define WS_BPACK  (WS_U2B1 + (Q_ + NT + 1) / 2)     // 1000132
#define WS_W0     (WS_BPACK + 8192)                 // 1008324
#define WS_BETA   (WS_W0 + K_)
#define WS_PART   (WS_BETA + K_)
#define WS_PART2  (WS_PART + 2048)

typedef __attribute__((ext_vector_type(8))) __bf16 bf16x8;
typedef __attribute__((ext_vector_type(4))) float  f32x4;

__device__ __forceinline__ float softplusf(float x) {
    return (x > 20.f) ? x : log1pf(__expf(x));
}

__device__ __forceinline__ unsigned short f2bf(float f) {
    unsigned int u = __float_as_uint(f);
    u = u + 0x7FFFu + ((u >> 16) & 1u);   // RNE (positive normals here)
    return (unsigned short)(u >> 16);
}

// Kernel A: u2[i] = (r[i+1]-a0-a1*r[i])^2; fp32 + two bf16 copies.
// Per-block reduction -> plain partial stores (NO atomics — R3 showed the
// per-wave same-cacheline atomics serialized at ~31 cyc each = 201 us).
__global__ void k_u2(const float* __restrict__ r,
                     const float* __restrict__ a0p,
                     const float* __restrict__ a1p,
                     float* __restrict__ ws) {
    __shared__ float red[8];
    int i = blockIdx.x * blockDim.x + threadIdx.x;
    float a0 = a0p[0], a1 = a1p[0];
    float v = 0.f, v2 = 0.f;
    if (i < NT) {
        float u  = r[i + 1] - a0 - a1 * r[i];
        float u2 = u * u;
        ws[WS_U2 + Q_ + i] = u2;
        unsigned short b = f2bf(u2);
        ((unsigned short*)(ws + WS_U2B0))[Q_ + i]     = b;
        ((unsigned short*)(ws + WS_U2B1))[Q_ + i - 1] = b;   // [e] = u2f[e+1]
        v = u2; v2 = u2 * u2;
    }
    #pragma unroll
    for (int off = 32; off > 0; off >>= 1) {
        v  += __shfl_down(v,  off, 64);
        v2 += __shfl_down(v2, off, 64);
    }
    int wv = threadIdx.x >> 6;
    if ((threadIdx.x & 63) == 0) { red[wv * 2] = v; red[wv * 2 + 1] = v2; }
    __syncthreads();
    if (threadIdx.x == 0) {
        ws[WS_PART  + blockIdx.x] = red[0] + red[2] + red[4] + red[6];
        ws[WS_PART2 + blockIdx.x] = red[1] + red[3] + red[5] + red[7];
    }
}

// Kernel B: pack B fragments (bf16), softplus w0/beta, var-init entries, beta0.
// Bpack layout: frag (kc,s): 64 lanes x 8 bf16, entry
//   Bpack[((kc*2+s)*64 + l)*8 + jj] = W'[32s + 8*(l>>4) + jj][kc*16 + (l&15)]
// where W'[j][kout] = softplus(raw_w[kout][63-j]).
// The var branch is one aligned full wave (threads 16896..16959): it reduces
// the NBLK partials itself (strided loads + butterfly) — no atomics.
__global__ void k_prep(const float* __restrict__ raw_beta0,
                       const float* __restrict__ raw_beta,
                       const float* __restrict__ raw_w0,
                       const float* __restrict__ raw_w,
                       float* __restrict__ ws,
                       float* __restrict__ out) {
    int idx = blockIdx.x * blockDim.x + threadIdx.x;
    if (idx < 16384) {
        int jj = idx & 7, l = (idx >> 3) & 63, s = (idx >> 9) & 1, kc = idx >> 10;
        int j    = 32 * s + 8 * (l >> 4) + jj;
        int kout = kc * 16 + (l & 15);
        ((unsigned short*)(ws + WS_BPACK))[idx] =
            f2bf(softplusf(raw_w[kout * Q_ + (Q_ - 1 - j)]));
    } else if (idx < 16384 + K_) {
        int k = idx - 16384;
        ws[WS_W0 + k] = softplusf(raw_w0[k]);
    } else if (idx < 16384 + 2 * K_) {
        int k = idx - (16384 + K_);
        ws[WS_BETA + k] = softplusf(raw_beta[k]);
    } else if (idx < 16384 + 2 * K_ + Q_) {
        int j = idx - (16384 + 2 * K_);   // 0..63 == lane id (aligned wave)
        float s1 = 0.f, s2 = 0.f;
        for (int p = j; p < NBLK; p += 64) {
            s1 += ws[WS_PART  + p];
            s2 += ws[WS_PART2 + p];
        }
        #pragma unroll
        for (int mask = 1; mask < 64; mask <<= 1) {
            s1 += __shfl_xor(s1, mask, 64);
            s2 += __shfl_xor(s2, mask, 64);
        }
        float n  = (float)NT;
        float var = (s2 - s1 * s1 / n) / (n - 1.f);
        unsigned short b = f2bf(var);
        ((unsigned short*)(ws + WS_U2B0))[j] = b;
        if (j < Q_ - 1) ((unsigned short*)(ws + WS_U2B1))[j] = b;
        if (j == 0) {
            ws[WS_BETA0] = softplusf(raw_beta0[0]);
            out[0] = 0.5f * n * 1.8378770664093453f;   // 0.5*n*log(2*pi)
        }
    }
}

// Kernel C: bf16 MFMA sliding-window GEMM + fused NLL epilogue.
// Block = 4 waves; wave w owns kout tiles kc = 4w..4w+3 (B frags in VGPRs).
// NO in-loop barrier (R4: per-iter __syncthreads lockstepped the 4 waves ->
// MfmaUtil 12%). Each wave writes per-tile partial sums to a wave-private
// LDS slab; ONE barrier at the end; 256-thread epilogue (thread owns one t).
__launch_bounds__(256, 4)
__global__ void k_main(const float* __restrict__ ws, float* __restrict__ out) {
    __shared__ __align__(16) float sigbuf[4][TT_][16];   // [wave][tile][t] 4 KB
    __shared__ float red[4];

    int tid = threadIdx.x;
    int l = tid & 63, w = tid >> 6;
    int m = l & 15, q = l >> 4;

    const unsigned short* __restrict__ bp = (const unsigned short*)(ws + WS_BPACK);
    const float* __restrict__ w0  = ws + WS_W0;
    const float* __restrict__ bet = ws + WS_BETA;
    const float* __restrict__ u2f = ws + WS_U2;
    float beta0v = ws[WS_BETA0];

    // Preload B fragments (4 tiles x 2 k-slices) and per-lane beta/w0.
    bf16x8 Bf[4][2];
    float betv[4], w0v[4];
    #pragma unroll
    for (int i = 0; i < 4; ++i) {
        int kc = w * 4 + i;
        #pragma unroll
        for (int s = 0; s < 2; ++s)
            __builtin_memcpy(&Bf[i][s], bp + ((kc * 2 + s) * 64 + l) * 8, 16);
        betv[i] = bet[kc * 16 + m];
        w0v[i]  = w0[kc * 16 + m];
    }

    // A-fragment addressing: lane needs u2full[s0 .. s0+7], s0 = t0+m+8q (+32).
    // parity(s0) = m&1 (t0 multiple of 16): even -> u2b0[s0], odd -> u2b1[s0-1].
    int par = m & 1;
    const char* abase = (const char*)(ws + (par ? WS_U2B1 : WS_U2B0));
    int tile0 = blockIdx.x * TT_;
    int aoff = (tile0 * 16 + m + 8 * q - par) * 2;   // bytes

    // Out-of-range tiles (last block) read garbage that stays inside ws and is
    // masked in the epilogue (t >= NT contributes 0) — no in-loop branch.
    #pragma unroll 2
    for (int it = 0; it < TT_; ++it) {
        bf16x8 A0, A1;
        __builtin_memcpy(&A0, abase + aoff, 16);
        __builtin_memcpy(&A1, abase + aoff + 64, 16);   // +32 elements

        float p[4] = {0.f, 0.f, 0.f, 0.f};
        #pragma unroll
        for (int i = 0; i < 4; ++i) {
            f32x4 acc = {w0v[i], w0v[i], w0v[i], w0v[i]};
            acc = __builtin_amdgcn_mfma_f32_16x16x32_bf16(A0, Bf[i][0], acc, 0, 0, 0);
            acc = __builtin_amdgcn_mfma_f32_16x16x32_bf16(A1, Bf[i][1], acc, 0, 0, 0);
            #pragma unroll
            for (int rr = 0; rr < 4; ++rr)
                p[rr] = fmaf(betv[i], fmaxf(acc[rr], 0.f), p[rr]);
        }
        // reduce across the 16 cols this wave owns (lanes within row group)
        #pragma unroll
        for (int mask = 1; mask < 16; mask <<= 1) {
            #pragma unroll
            for (int rr = 0; rr < 4; ++rr)
                p[rr] += __shfl_xor(p[rr], mask, 64);
        }
        if (m == 0) {
            float4 v4 = make_float4(p[0], p[1], p[2], p[3]);
            *(float4*)&sigbuf[w][it][q * 4] = v4;        // rows q*4..q*4+3
        }
        aoff += 32;
    }

    __syncthreads();   // the ONLY barrier

    // Epilogue: thread tid owns t = tile0*16 + tid (256 t's = TT_ tiles).
    int tile = tid >> 4, tt = tid & 15;
    int t = tile0 * 16 + tid;
    float s = sigbuf[0][tile][tt] + sigbuf[1][tile][tt]
            + sigbuf[2][tile][tt] + sigbuf[3][tile][tt];
    float sg = beta0v + s + 1e-8f;
    float val = (t < NT) ? (__logf(sg) + u2f[Q_ + t] / sg) : 0.f;

    #pragma unroll
    for (int mask = 1; mask < 64; mask <<= 1)
        val += __shfl_xor(val, mask, 64);
    if (l == 0) red[w] = val;
    __syncthreads();
    if (tid == 0) atomicAdd(out, 0.5f * (red[0] + red[1] + red[2] + red[3]));
}

extern "C" void kernel_launch(void* const* d_in, const int* in_sizes, int n_in,
                              void* d_out, int out_size, void* d_ws, size_t ws_size,
                              hipStream_t stream) {
    const float* r        = (const float*)d_in[0];
    const float* a0       = (const float*)d_in[1];
    const float* a1       = (const float*)d_in[2];
    const float* raw_b0   = (const float*)d_in[3];
    const float* raw_beta = (const float*)d_in[4];
    const float* raw_w0   = (const float*)d_in[5];
    const float* raw_w    = (const float*)d_in[6];
    float* out = (float*)d_out;
    float* ws  = (float*)d_ws;

    k_u2<<<NBLK, 256, 0, stream>>>(r, a0, a1, ws);

    int prep_threads = 16384 + 2 * K_ + Q_;   // 16960
    k_prep<<<(prep_threads + 255) / 256, 256, 0, stream>>>(
        raw_b0, raw_beta, raw_w0, raw_w, ws, out);

    int grid = (NTILES + TT_ - 1) / TT_;      // 1954
    k_main<<<grid, 256, 0, stream>>>(ws, out);
}

// Round 6
// 103.643 us; speedup vs baseline: 4.9910x; 1.1426x over previous
//
#include <hip/hip_runtime.h>
#include <math.h>

// Problem constants (reference: K=256, Q=64, T=500001 -> n = 500000)
#define K_ 256
#define Q_ 64
#define NT 500000
#define NTILES (NT / 16)      // 31250 t-tiles of 16
#define TT_ 16                // t-tiles per block
#define NBLK ((NT + 255) / 256)          // 1954 k_u2 blocks
#define GRID_MAIN ((NTILES + TT_ - 1) / TT_)   // 1954 k_main blocks

// Workspace layout (float offsets):
//  [2]  softplus(raw_beta0)
//  [WS_U2   .. +Q_+NT)   u2_full fp32
//  [WS_U2B0 .. )         bf16 u2_full            (ushort, len Q_+NT)
//  [WS_U2B1 .. )         bf16 u2_full shifted+1  (ushort, len Q_+NT; [e]=u2f[e+1])
//  [WS_BPACK .. )        W in MFMA fragment order (ushort, 16*2*64*8 = 16384)
//  [WS_W0 .. +K_)        softplus(raw_w0) fp32
//  [WS_BETA .. +K_)      softplus(raw_beta) fp32
//  [WS_PART/2 .. +2048)  per-block sum(u2), sum(u2^2) partials
//  [WS_OUT .. +2048)     per-block NLL partials (k_main -> k_final)
#define WS_BETA0  2
#define WS_U2     4
#define WS_U2B0   (WS_U2 + Q_ + NT)                 // 500068
#define WS_U2B1   (WS_U2B0 + (Q_ + NT + 1) / 2)     // 750100
#define WS_BPACK  (WS_U2B1 + (Q_ + NT + 1) / 2)     // 1000132
#define WS_W0     (WS_BPACK + 8192)                 // 1008324
#define WS_BETA   (WS_W0 + K_)
#define WS_PART   (WS_BETA + K_)
#define WS_PART2  (WS_PART + 2048)
#define WS_OUT    (WS_PART2 + 2048)

typedef __attribute__((ext_vector_type(8))) __bf16 bf16x8;
typedef __attribute__((ext_vector_type(4))) float  f32x4;

__device__ __forceinline__ float softplusf(float x) {
    return (x > 20.f) ? x : log1pf(__expf(x));
}

__device__ __forceinline__ unsigned short f2bf(float f) {
    unsigned int u = __float_as_uint(f);
    u = u + 0x7FFFu + ((u >> 16) & 1u);   // RNE (positive normals here)
    return (unsigned short)(u >> 16);
}

// Kernel A: u2[i] = (r[i+1]-a0-a1*r[i])^2; fp32 + two bf16 copies.
// Per-block reduction -> plain partial stores (NO atomics — R3: same-line
// atomics serialize at ~31 cyc each).
__global__ void k_u2(const float* __restrict__ r,
                     const float* __restrict__ a0p,
                     const float* __restrict__ a1p,
                     float* __restrict__ ws) {
    __shared__ float red[8];
    int i = blockIdx.x * blockDim.x + threadIdx.x;
    float a0 = a0p[0], a1 = a1p[0];
    float v = 0.f, v2 = 0.f;
    if (i < NT) {
        float u  = r[i + 1] - a0 - a1 * r[i];
        float u2 = u * u;
        ws[WS_U2 + Q_ + i] = u2;
        unsigned short b = f2bf(u2);
        ((unsigned short*)(ws + WS_U2B0))[Q_ + i]     = b;
        ((unsigned short*)(ws + WS_U2B1))[Q_ + i - 1] = b;   // [e] = u2f[e+1]
        v = u2; v2 = u2 * u2;
    }
    #pragma unroll
    for (int off = 32; off > 0; off >>= 1) {
        v  += __shfl_down(v,  off, 64);
        v2 += __shfl_down(v2, off, 64);
    }
    int wv = threadIdx.x >> 6;
    if ((threadIdx.x & 63) == 0) { red[wv * 2] = v; red[wv * 2 + 1] = v2; }
    __syncthreads();
    if (threadIdx.x == 0) {
        ws[WS_PART  + blockIdx.x] = red[0] + red[2] + red[4] + red[6];
        ws[WS_PART2 + blockIdx.x] = red[1] + red[3] + red[5] + red[7];
    }
}

// Kernel B: pack W fragments (bf16), softplus w0/beta, var-init entries, beta0.
// Wpack layout (A/B-symmetric MFMA operand order):
//   Wpack[((kc*2+s)*64 + l)*8 + jj] = W'[32s + 8*(l>>4) + jj][kc*16 + (l&15)]
// where W'[j][kout] = softplus(raw_w[kout][63-j]).
__global__ void k_prep(const float* __restrict__ raw_beta0,
                       const float* __restrict__ raw_beta,
                       const float* __restrict__ raw_w0,
                       const float* __restrict__ raw_w,
                       float* __restrict__ ws) {
    int idx = blockIdx.x * blockDim.x + threadIdx.x;
    if (idx < 16384) {
        int jj = idx & 7, l = (idx >> 3) & 63, s = (idx >> 9) & 1, kc = idx >> 10;
        int j    = 32 * s + 8 * (l >> 4) + jj;
        int kout = kc * 16 + (l & 15);
        ((unsigned short*)(ws + WS_BPACK))[idx] =
            f2bf(softplusf(raw_w[kout * Q_ + (Q_ - 1 - j)]));
    } else if (idx < 16384 + K_) {
        int k = idx - 16384;
        ws[WS_W0 + k] = softplusf(raw_w0[k]);
    } else if (idx < 16384 + 2 * K_) {
        int k = idx - (16384 + K_);
        ws[WS_BETA + k] = softplusf(raw_beta[k]);
    } else if (idx < 16384 + 2 * K_ + Q_) {
        int j = idx - (16384 + 2 * K_);   // 0..63 == lane id (aligned wave)
        float s1 = 0.f, s2 = 0.f;
        for (int p = j; p < NBLK; p += 64) {
            s1 += ws[WS_PART  + p];
            s2 += ws[WS_PART2 + p];
        }
        #pragma unroll
        for (int mask = 1; mask < 64; mask <<= 1) {
            s1 += __shfl_xor(s1, mask, 64);
            s2 += __shfl_xor(s2, mask, 64);
        }
        float n  = (float)NT;
        float var = (s2 - s1 * s1 / n) / (n - 1.f);
        unsigned short b = f2bf(var);
        ((unsigned short*)(ws + WS_U2B0))[j] = b;
        if (j < Q_ - 1) ((unsigned short*)(ws + WS_U2B1))[j] = b;
        if (j == 0) ws[WS_BETA0] = softplusf(raw_beta0[0]);
    }
}

// Kernel C: bf16 MFMA sliding-window GEMM + fused NLL partial.
// OPERAND SWAP vs R5: W is the A-operand, u2 window the B-operand, so
// C/D rows (quad*4+reg) = kout, cols (lane&15) = t. The k-reduction is
// within-lane (4 regs x 4 kc) — NO in-loop cross-lane ops, no butterfly.
// acc initialized through the MFMA C-operand (w0c) — no per-tile movs.
// Per tile per lane: 8 MFMA + 16 fmax/16 fma + 3 add + 1 ds_write.
// Per-block result -> plain partial store (atomic wall removed; k_final sums).
__launch_bounds__(256, 4)
__global__ void k_main(float* __restrict__ ws) {
    __shared__ __align__(16) float sig[TT_ * 256];   // 16 KB
    __shared__ float red[4];

    int tid = threadIdx.x;
    int l = tid & 63, w = tid >> 6;
    int m = l & 15, q = l >> 4;

    const unsigned short* bp = (const unsigned short*)(ws + WS_BPACK);
    const float* u2f = ws + WS_U2;
    float beta0v = ws[WS_BETA0];

    // Preload W fragments (A-operand) and per-lane w0/beta float4s
    // (kout = kc*16 + q*4 + rr  ->  q-dependent vector loads, 16B aligned).
    bf16x8 Wf[4][2];
    f32x4 w0c[4], betc[4];
    #pragma unroll
    for (int i = 0; i < 4; ++i) {
        int kc = w * 4 + i;
        #pragma unroll
        for (int s = 0; s < 2; ++s)
            __builtin_memcpy(&Wf[i][s], bp + ((kc * 2 + s) * 64 + l) * 8, 16);
        w0c[i] = *(const f32x4*)(ws + WS_W0   + kc * 16 + q * 4);
        betc[i] = *(const f32x4*)(ws + WS_BETA + kc * 16 + q * 4);
    }

    // u2 B-fragment: lane needs u2full[s0..s0+7], s0 = t0 + m + 8q (+32).
    // parity(s0)=m&1: even -> u2b0[s0], odd -> u2b1[s0-1] (4B-aligned loads).
    int par = m & 1;
    const char* abase = (const char*)(ws + (par ? WS_U2B1 : WS_U2B0));
    int tile0 = blockIdx.x * TT_;
    int aoff = (tile0 * 16 + m + 8 * q - par) * 2;   // bytes

    bf16x8 U0, U1, U0n, U1n;
    __builtin_memcpy(&U0, abase + aoff, 16);
    __builtin_memcpy(&U1, abase + aoff + 64, 16);

    // Last block: reads past the valid range stay inside ws (garbage masked
    // in the epilogue), including the one-tile prefetch overshoot.
    #pragma unroll 2
    for (int it = 0; it < TT_; ++it) {
        int anext = aoff + 32;
        __builtin_memcpy(&U0n, abase + anext, 16);
        __builtin_memcpy(&U1n, abase + anext + 64, 16);

        float p[4];
        #pragma unroll
        for (int i = 0; i < 4; ++i) {
            f32x4 acc = __builtin_amdgcn_mfma_f32_16x16x32_bf16(Wf[i][0], U0, w0c[i], 0, 0, 0);
            acc = __builtin_amdgcn_mfma_f32_16x16x32_bf16(Wf[i][1], U1, acc, 0, 0, 0);
            float pi;
            pi = betc[i][0] * fmaxf(acc[0], 0.f);
            pi = fmaf(betc[i][1], fmaxf(acc[1], 0.f), pi);
            pi = fmaf(betc[i][2], fmaxf(acc[2], 0.f), pi);
            pi = fmaf(betc[i][3], fmaxf(acc[3], 0.f), pi);
            p[i] = pi;
        }
        sig[it * 256 + tid] = (p[0] + p[1]) + (p[2] + p[3]);

        aoff = anext; U0 = U0n; U1 = U1n;
    }

    __syncthreads();   // the ONLY barrier before epilogue

    // Epilogue: thread tid owns t = tile0*16 + tid; sum its 16 partials.
    int tile = tid >> 4, tt = tid & 15;
    const float* sp = &sig[tile * 256 + tt];
    float s = 0.f;
    #pragma unroll
    for (int wq = 0; wq < 16; ++wq) s += sp[wq * 16];
    float sg = beta0v + s + 1e-8f;
    int t = tile0 * 16 + tid;
    float val = (t < NT) ? (__logf(sg) + u2f[Q_ + t] / sg) : 0.f;

    #pragma unroll
    for (int mask = 1; mask < 64; mask <<= 1)
        val += __shfl_xor(val, mask, 64);
    if (l == 0) red[w] = val;
    __syncthreads();
    if (tid == 0)
        ws[WS_OUT + blockIdx.x] = red[0] + red[1] + red[2] + red[3];
}

// Kernel D: sum the per-block NLL partials, add the constant, write out[0].
__global__ void k_final(const float* __restrict__ ws, float* __restrict__ out) {
    __shared__ float red[4];
    int tid = threadIdx.x;
    float s = 0.f;
    for (int p = tid; p < GRID_MAIN; p += 256) s += ws[WS_OUT + p];
    #pragma unroll
    for (int mask = 1; mask < 64; mask <<= 1)
        s += __shfl_xor(s, mask, 64);
    if ((tid & 63) == 0) red[tid >> 6] = s;
    __syncthreads();
    if (tid == 0)
        out[0] = 0.5f * (float)NT * 1.8378770664093453f
               + 0.5f * (red[0] + red[1] + red[2] + red[3]);
}

extern "C" void kernel_launch(void* const* d_in, const int* in_sizes, int n_in,
                              void* d_out, int out_size, void* d_ws, size_t ws_size,
                              hipStream_t stream) {
    const float* r        = (const float*)d_in[0];
    const float* a0       = (const float*)d_in[1];
    const float* a1       = (const float*)d_in[2];
    const float* raw_b0   = (const float*)d_in[3];
    const float* raw_beta = (const float*)d_in[4];
    const float* raw_w0   = (const float*)d_in[5];
    const float* raw_w    = (const float*)d_in[6];
    float* out = (float*)d_out;
    float* ws  = (float*)d_ws;

    k_u2<<<NBLK, 256, 0, stream>>>(r, a0, a1, ws);

    int prep_threads = 16384 + 2 * K_ + Q_;   // 16960
    k_prep<<<(prep_threads + 255) / 256, 256, 0, stream>>>(
        raw_b0, raw_beta, raw_w0, raw_w, ws);

    k_main<<<GRID_MAIN, 256, 0, stream>>>(ws);

    k_final<<<1, 256, 0, stream>>>(ws, out);
}